// Round 1
// baseline (1149.121 us; speedup 1.0000x reference)
//
#include <hip/hip_runtime.h>

// SparseGraphWaveletLayer: out = relu( (phi·diag(theta)) @ (phi_inv @ (F_sparse @ W)) )
// N=50000 nodes, IN_CH=256, OUT_CH=128, NNZ=800000 per sparse matrix.
//
// Round 0: correctness-first atomic-scatter COO SpMM chain.
//   stage1: filtered[r,:] += v * W[c,:]          (c in [0,256))
//   stage2: tmp[r,:]      += v * filtered[c,:]   (c in [0,N))
//   stage3: out[r,:]      += v*theta[c] * tmp[c,:]
//   stage4: out = relu(out)
// One thread per (edge, feature): lane = feature -> coalesced gather + atomic.

#define OUT_CH 128

__global__ __launch_bounds__(256) void spmm_atomic_kernel(
    const int* __restrict__ rows,
    const int* __restrict__ cols,
    const float* __restrict__ vals,
    const float* __restrict__ theta,   // nullptr for stages 1-2
    const float* __restrict__ dense,   // [*, OUT_CH] gather source
    float* __restrict__ out,           // [N, OUT_CH] scatter-add dest
    int nnz)
{
    int idx = blockIdx.x * blockDim.x + threadIdx.x;
    int e = idx >> 7;          // edge id   (OUT_CH == 128)
    int f = idx & (OUT_CH - 1);
    if (e >= nnz) return;
    int r = rows[e];
    int c = cols[e];
    float v = vals[e];
    if (theta != nullptr) v *= theta[c];
    float contrib = v * dense[(size_t)c * OUT_CH + f];
    atomicAdd(&out[(size_t)r * OUT_CH + f], contrib);
}

__global__ __launch_bounds__(256) void relu_kernel(float* __restrict__ out, int n4)
{
    int i = blockIdx.x * blockDim.x + threadIdx.x;
    if (i >= n4) return;
    float4 v = ((float4*)out)[i];
    v.x = fmaxf(v.x, 0.0f);
    v.y = fmaxf(v.y, 0.0f);
    v.z = fmaxf(v.z, 0.0f);
    v.w = fmaxf(v.w, 0.0f);
    ((float4*)out)[i] = v;
}

extern "C" void kernel_launch(void* const* d_in, const int* in_sizes, int n_in,
                              void* d_out, int out_size, void* d_ws, size_t ws_size,
                              hipStream_t stream)
{
    const int*   phi_idx    = (const int*)d_in[0];    // [2, NNZ]: rows then cols
    const float* phi_vals   = (const float*)d_in[1];  // [NNZ]
    const int*   phii_idx   = (const int*)d_in[2];    // [2, NNZ]
    const float* phii_vals  = (const float*)d_in[3];  // [NNZ]
    const int*   feat_idx   = (const int*)d_in[4];    // [2, NNZ]: node idx, feature col
    const float* feat_vals  = (const float*)d_in[5];  // [NNZ]
    const float* W          = (const float*)d_in[6];  // [256, 128]
    const float* theta      = (const float*)d_in[7];  // [N]
    // d_in[8] = dropout scalar, identity in eval mode: ignored.

    const int nnz_phi  = in_sizes[1];
    const int nnz_phii = in_sizes[3];
    const int nnz_feat = in_sizes[5];
    const int n_nodes  = in_sizes[7];
    const size_t dense_elems = (size_t)n_nodes * OUT_CH;   // == out_size

    float* filtered = (float*)d_ws;                        // [N, 128]
    float* tmp      = filtered + dense_elems;              // [N, 128]

    // zero accumulators (d_out/d_ws are re-poisoned to 0xAA before every call)
    hipMemsetAsync(filtered, 0, 2 * dense_elems * sizeof(float), stream);
    hipMemsetAsync(d_out, 0, (size_t)out_size * sizeof(float), stream);

    dim3 block(256);

    // stage 1: filtered = F_sparse @ W
    {
        long long threads = (long long)nnz_feat * OUT_CH;
        dim3 grid((unsigned)((threads + 255) / 256));
        spmm_atomic_kernel<<<grid, block, 0, stream>>>(
            feat_idx, feat_idx + nnz_feat, feat_vals, nullptr, W, filtered, nnz_feat);
    }
    // stage 2: tmp = phi_inv @ filtered
    {
        long long threads = (long long)nnz_phii * OUT_CH;
        dim3 grid((unsigned)((threads + 255) / 256));
        spmm_atomic_kernel<<<grid, block, 0, stream>>>(
            phii_idx, phii_idx + nnz_phii, phii_vals, nullptr, filtered, tmp, nnz_phii);
    }
    // stage 3: out = (phi * diag(theta)) @ tmp
    {
        long long threads = (long long)nnz_phi * OUT_CH;
        dim3 grid((unsigned)((threads + 255) / 256));
        spmm_atomic_kernel<<<grid, block, 0, stream>>>(
            phi_idx, phi_idx + nnz_phi, phi_vals, theta, tmp, (float*)d_out, nnz_phi);
    }
    // stage 4: relu in place
    {
        int n4 = out_size / 4;
        dim3 grid((n4 + 255) / 256);
        relu_kernel<<<grid, block, 0, stream>>>((float*)d_out, n4);
    }
}

// Round 2
// 563.361 us; speedup vs baseline: 2.0398x; 2.0398x over previous
//
#include <hip/hip_runtime.h>

// SparseGraphWaveletLayer: out = relu( (phi·diag(theta)) @ (phi_inv @ (F_sparse @ W)) )
// N=50000, IN_CH=256, OUT_CH=128, NNZ=800000 per sparse matrix.
//
// Round 1 -> 2: replace atomic-scatter SpMM (400 MB atomic write traffic per
// stage) with on-device CSR build + gather-side SpMM (one wave per row,
// register accumulation, single 512B row write). Theta folded into phi vals
// during CSR fill; ReLU fused into stage-3 store; no accumulator memsets.

#define OUT_CH 128
#define HALF_CH 64

// ---------------- CSR build ----------------

__global__ __launch_bounds__(256) void hist3_kernel(
    const int* __restrict__ r0, int n0, int* __restrict__ c0,
    const int* __restrict__ r1, int n1, int* __restrict__ c1,
    const int* __restrict__ r2, int n2, int* __restrict__ c2)
{
    int i = blockIdx.x * blockDim.x + threadIdx.x;
    if (i < n0) { atomicAdd(&c0[r0[i]], 1); return; }
    i -= n0;
    if (i < n1) { atomicAdd(&c1[r1[i]], 1); return; }
    i -= n1;
    if (i < n2) { atomicAdd(&c2[r2[i]], 1); }
}

// One block per matrix (grid=3). In-place exclusive scan of counts -> offsets,
// duplicate into cursor array for the fill pass. Wave-shuffle scan: 3 barriers
// per 1024-chunk.
__global__ __launch_bounds__(1024) void scan3_kernel(
    int* o0, int* u0, int* o1, int* u1, int* o2, int* u2, int n)
{
    int* off; int* cur;
    if (blockIdx.x == 0)      { off = o0; cur = u0; }
    else if (blockIdx.x == 1) { off = o1; cur = u1; }
    else                      { off = o2; cur = u2; }

    const int tid  = threadIdx.x;
    const int lane = tid & 63;
    const int wid  = tid >> 6;            // 16 waves
    __shared__ int wsum[17];
    int carry = 0;
    for (int base = 0; base < n; base += 1024) {
        int i = base + tid;
        int x = (i < n) ? off[i] : 0;
        int orig = x;
        #pragma unroll
        for (int s = 1; s < 64; s <<= 1) {     // wave-inclusive scan
            int y = __shfl_up(x, s);
            if (lane >= s) x += y;
        }
        if (lane == 63) wsum[wid] = x;
        __syncthreads();
        if (tid == 0) {
            int run = 0;
            #pragma unroll
            for (int w = 0; w < 16; ++w) { int t = wsum[w]; wsum[w] = run; run += t; }
            wsum[16] = run;
        }
        __syncthreads();
        int excl = carry + wsum[wid] + x - orig;
        if (i < n) { off[i] = excl; cur[i] = excl; }
        carry += wsum[16];
        __syncthreads();   // wsum reused next chunk
    }
    if (tid == 0) off[n] = carry;
}

// Permuted fill: edges[pos] = (col, val_bits), theta folded into matrix 2.
__global__ __launch_bounds__(256) void fill3_kernel(
    const int* __restrict__ r0, const int* __restrict__ col0, const float* __restrict__ v0,
    int n0, int* __restrict__ cur0, int2* __restrict__ e0,
    const int* __restrict__ r1, const int* __restrict__ col1, const float* __restrict__ v1,
    int n1, int* __restrict__ cur1, int2* __restrict__ e1,
    const int* __restrict__ r2, const int* __restrict__ col2, const float* __restrict__ v2,
    int n2, int* __restrict__ cur2, int2* __restrict__ e2,
    const float* __restrict__ theta)
{
    int i = blockIdx.x * blockDim.x + threadIdx.x;
    if (i < n0) {
        int pos = atomicAdd(&cur0[r0[i]], 1);
        e0[pos] = make_int2(col0[i], __float_as_int(v0[i]));
        return;
    }
    i -= n0;
    if (i < n1) {
        int pos = atomicAdd(&cur1[r1[i]], 1);
        e1[pos] = make_int2(col1[i], __float_as_int(v1[i]));
        return;
    }
    i -= n1;
    if (i < n2) {
        int c = col2[i];
        int pos = atomicAdd(&cur2[r2[i]], 1);
        e2[pos] = make_int2(c, __float_as_int(v2[i] * theta[c]));
    }
}

// ---------------- gather-side CSR SpMM ----------------
// One wave per row; lane handles 2 features (float2). Uniform broadcast load
// of each edge (int2), coalesced 512B gather of the source row, single
// 512B row store. No atomics, no zero-init needed.
template<bool RELU>
__global__ __launch_bounds__(256) void spmm_csr_kernel(
    const int* __restrict__ off, const int2* __restrict__ edges,
    const float* __restrict__ dense, float* __restrict__ out, int nrows)
{
    int lane = threadIdx.x & 63;
    int r = blockIdx.x * 4 + (threadIdx.x >> 6);
    if (r >= nrows) return;
    int j = off[r], end = off[r + 1];
    const float2* __restrict__ d2 = (const float2*)dense;
    float2 acc0 = make_float2(0.f, 0.f);
    float2 acc1 = make_float2(0.f, 0.f);
    for (; j + 2 <= end; j += 2) {           // unroll 2: two gathers in flight
        int2 ea = edges[j], eb = edges[j + 1];
        float2 da = d2[(size_t)ea.x * HALF_CH + lane];
        float2 db = d2[(size_t)eb.x * HALF_CH + lane];
        float va = __int_as_float(ea.y), vb = __int_as_float(eb.y);
        acc0.x = fmaf(va, da.x, acc0.x); acc0.y = fmaf(va, da.y, acc0.y);
        acc1.x = fmaf(vb, db.x, acc1.x); acc1.y = fmaf(vb, db.y, acc1.y);
    }
    if (j < end) {
        int2 ea = edges[j];
        float2 da = d2[(size_t)ea.x * HALF_CH + lane];
        float va = __int_as_float(ea.y);
        acc0.x = fmaf(va, da.x, acc0.x); acc0.y = fmaf(va, da.y, acc0.y);
    }
    float2 res = make_float2(acc0.x + acc1.x, acc0.y + acc1.y);
    if (RELU) { res.x = fmaxf(res.x, 0.f); res.y = fmaxf(res.y, 0.f); }
    ((float2*)out)[(size_t)r * HALF_CH + lane] = res;
}

// ---------------- fallback (round-0) atomic path ----------------

__global__ __launch_bounds__(256) void spmm_atomic_kernel(
    const int* __restrict__ rows, const int* __restrict__ cols,
    const float* __restrict__ vals, const float* __restrict__ theta,
    const float* __restrict__ dense, float* __restrict__ out, int nnz)
{
    int idx = blockIdx.x * blockDim.x + threadIdx.x;
    int e = idx >> 7;
    int f = idx & (OUT_CH - 1);
    if (e >= nnz) return;
    int r = rows[e];
    int c = cols[e];
    float v = vals[e];
    if (theta != nullptr) v *= theta[c];
    atomicAdd(&out[(size_t)r * OUT_CH + f], v * dense[(size_t)c * OUT_CH + f]);
}

__global__ __launch_bounds__(256) void relu_kernel(float* __restrict__ out, int n4)
{
    int i = blockIdx.x * blockDim.x + threadIdx.x;
    if (i >= n4) return;
    float4 v = ((float4*)out)[i];
    v.x = fmaxf(v.x, 0.f); v.y = fmaxf(v.y, 0.f);
    v.z = fmaxf(v.z, 0.f); v.w = fmaxf(v.w, 0.f);
    ((float4*)out)[i] = v;
}

// ---------------- launch ----------------

static inline size_t align16(size_t x) { return (x + 15) & ~(size_t)15; }

extern "C" void kernel_launch(void* const* d_in, const int* in_sizes, int n_in,
                              void* d_out, int out_size, void* d_ws, size_t ws_size,
                              hipStream_t stream)
{
    const int*   phi_idx   = (const int*)d_in[0];
    const float* phi_vals  = (const float*)d_in[1];
    const int*   phii_idx  = (const int*)d_in[2];
    const float* phii_vals = (const float*)d_in[3];
    const int*   feat_idx  = (const int*)d_in[4];
    const float* feat_vals = (const float*)d_in[5];
    const float* W         = (const float*)d_in[6];
    const float* theta     = (const float*)d_in[7];

    const int nnz_phi  = in_sizes[1];
    const int nnz_phii = in_sizes[3];
    const int nnz_feat = in_sizes[5];
    const int n_nodes  = in_sizes[7];
    const size_t dense_elems = (size_t)n_nodes * OUT_CH;

    // ---- workspace layout ----
    size_t p = 0;
    size_t filtered_off = p; p += align16(dense_elems * sizeof(float));
    size_t tmp_off      = p; p += align16(dense_elems * sizeof(float));
    size_t offs_off     = p; p += align16((size_t)3 * (n_nodes + 1) * sizeof(int)); // 3 contiguous offset arrays
    size_t curs_off     = p; p += align16((size_t)3 * (n_nodes + 1) * sizeof(int));
    size_t ef_off       = p; p += align16((size_t)nnz_feat * sizeof(int2));
    size_t epi_off      = p; p += align16((size_t)nnz_phii * sizeof(int2));
    size_t ep_off       = p; p += align16((size_t)nnz_phi  * sizeof(int2));
    size_t need = p;

    char* ws = (char*)d_ws;
    dim3 block(256);

    if (ws_size >= need) {
        float* filtered = (float*)(ws + filtered_off);
        float* tmp      = (float*)(ws + tmp_off);
        int* off_f  = (int*)(ws + offs_off);
        int* off_pi = off_f  + (n_nodes + 1);
        int* off_p  = off_pi + (n_nodes + 1);
        int* cur_f  = (int*)(ws + curs_off);
        int* cur_pi = cur_f  + (n_nodes + 1);
        int* cur_p  = cur_pi + (n_nodes + 1);
        int2* e_f  = (int2*)(ws + ef_off);
        int2* e_pi = (int2*)(ws + epi_off);
        int2* e_p  = (int2*)(ws + ep_off);

        // zero the 3 count/offset arrays (contiguous)
        hipMemsetAsync(off_f, 0, (size_t)3 * (n_nodes + 1) * sizeof(int), stream);

        long long total = (long long)nnz_feat + nnz_phii + nnz_phi;
        dim3 grid_e((unsigned)((total + 255) / 256));

        hist3_kernel<<<grid_e, block, 0, stream>>>(
            feat_idx, nnz_feat, off_f,
            phii_idx, nnz_phii, off_pi,
            phi_idx,  nnz_phi,  off_p);

        scan3_kernel<<<dim3(3), dim3(1024), 0, stream>>>(
            off_f, cur_f, off_pi, cur_pi, off_p, cur_p, n_nodes);

        fill3_kernel<<<grid_e, block, 0, stream>>>(
            feat_idx, feat_idx + nnz_feat, feat_vals, nnz_feat, cur_f,  e_f,
            phii_idx, phii_idx + nnz_phii, phii_vals, nnz_phii, cur_pi, e_pi,
            phi_idx,  phi_idx  + nnz_phi,  phi_vals,  nnz_phi,  cur_p,  e_p,
            theta);

        dim3 grid_r((unsigned)((n_nodes + 3) / 4));
        spmm_csr_kernel<false><<<grid_r, block, 0, stream>>>(off_f,  e_f,  W,        filtered, n_nodes);
        spmm_csr_kernel<false><<<grid_r, block, 0, stream>>>(off_pi, e_pi, filtered, tmp,      n_nodes);
        spmm_csr_kernel<true ><<<grid_r, block, 0, stream>>>(off_p,  e_p,  tmp,      (float*)d_out, n_nodes);
    } else {
        // fallback: round-0 atomic path (needs only 2 dense buffers)
        float* filtered = (float*)ws;
        float* tmp      = filtered + dense_elems;
        hipMemsetAsync(filtered, 0, 2 * dense_elems * sizeof(float), stream);
        hipMemsetAsync(d_out, 0, (size_t)out_size * sizeof(float), stream);
        {
            long long t = (long long)nnz_feat * OUT_CH;
            spmm_atomic_kernel<<<dim3((unsigned)((t + 255) / 256)), block, 0, stream>>>(
                feat_idx, feat_idx + nnz_feat, feat_vals, nullptr, W, filtered, nnz_feat);
        }
        {
            long long t = (long long)nnz_phii * OUT_CH;
            spmm_atomic_kernel<<<dim3((unsigned)((t + 255) / 256)), block, 0, stream>>>(
                phii_idx, phii_idx + nnz_phii, phii_vals, nullptr, filtered, tmp, nnz_phii);
        }
        {
            long long t = (long long)nnz_phi * OUT_CH;
            spmm_atomic_kernel<<<dim3((unsigned)((t + 255) / 256)), block, 0, stream>>>(
                phi_idx, phi_idx + nnz_phi, phi_vals, theta, tmp, (float*)d_out, nnz_phi);
        }
        {
            int n4 = out_size / 4;
            relu_kernel<<<dim3((n4 + 255) / 256), block, 0, stream>>>((float*)d_out, n4);
        }
    }
}

// Round 3
// 385.013 us; speedup vs baseline: 2.9846x; 1.4632x over previous
//
#include <hip/hip_runtime.h>

// SparseGraphWaveletLayer: out = relu( (phi·diag(theta)) @ (phi_inv @ (F_sparse @ W)) )
// N=50000, IN_CH=256, OUT_CH=128, NNZ=800000 per sparse matrix.
//
// Round 2 -> 3:
//  - hist pass stores each edge's within-row rank (atomicAdd return, u16)
//    so the fill pass needs NO atomics: pos = off[r] + rank[i].
//  - 3-block serial scan replaced by parallel 2-kernel scan (13 blocks x 3).
//  - SpMM: wave-uniform edge offsets via readfirstlane (scalar s_load of
//    (col,val)), unroll-4 gather loop.
//  - rank array overlaid on `tmp` (dead until spmm stage 2) -> ws need < round 2.

#define OUT_CH 128
#define HALF_CH 64
#define SCAN_TPB 256
#define SCAN_EPT 16
#define SCAN_CHUNK (SCAN_TPB * SCAN_EPT)   // 4096

// ---------------- CSR build ----------------

// Histogram + rank: rank[i] = old count (edge's slot within its row).
__global__ __launch_bounds__(256) void hist3_rank_kernel(
    const int* __restrict__ r0, int n0, int* __restrict__ c0,
    const int* __restrict__ r1, int n1, int* __restrict__ c1,
    const int* __restrict__ r2, int n2, int* __restrict__ c2,
    unsigned short* __restrict__ rank)
{
    int g = blockIdx.x * blockDim.x + threadIdx.x;
    int i = g;
    if (i < n0) { rank[g] = (unsigned short)atomicAdd(&c0[r0[i]], 1); return; }
    i -= n0;
    if (i < n1) { rank[g] = (unsigned short)atomicAdd(&c1[r1[i]], 1); return; }
    i -= n1;
    if (i < n2) { rank[g] = (unsigned short)atomicAdd(&c2[r2[i]], 1); }
}

// Block-local exclusive scan over 4096-element chunks; block totals -> partials.
// grid = (NB, 3): blockIdx.y selects which matrix's count array.
__global__ __launch_bounds__(SCAN_TPB) void scan_local_kernel(
    int* __restrict__ counts, int* __restrict__ partials, int n, int NB)
{
    int m = blockIdx.y;
    int* off = counts + (size_t)m * (n + 1);
    int tbase = blockIdx.x * SCAN_CHUNK + threadIdx.x * SCAN_EPT;

    int v[SCAN_EPT];
    int sum = 0;
    #pragma unroll
    for (int k = 0; k < SCAN_EPT; ++k) {
        int i = tbase + k;
        int x = (i < n) ? off[i] : 0;
        v[k] = x; sum += x;
    }
    int lane = threadIdx.x & 63, wid = threadIdx.x >> 6;
    int incl = sum;
    #pragma unroll
    for (int s = 1; s < 64; s <<= 1) {
        int y = __shfl_up(incl, s);
        if (lane >= s) incl += y;
    }
    __shared__ int wtot[4];
    if (lane == 63) wtot[wid] = incl;
    __syncthreads();
    int wbase = 0;
    for (int w = 0; w < wid; ++w) wbase += wtot[w];
    int run = wbase + incl - sum;          // thread-exclusive base within block
    #pragma unroll
    for (int k = 0; k < SCAN_EPT; ++k) {
        int i = tbase + k;
        if (i < n) off[i] = run;
        run += v[k];
    }
    if (threadIdx.x == SCAN_TPB - 1)
        partials[m * NB + blockIdx.x] = wbase + incl;   // block total
}

// Add cross-block prefix; block (0,m) thread 0 also writes off[n] = total.
__global__ __launch_bounds__(SCAN_TPB) void scan_fixup_kernel(
    int* __restrict__ counts, const int* __restrict__ partials, int n, int NB)
{
    int m = blockIdx.y;
    int* off = counts + (size_t)m * (n + 1);
    int prefix = 0, total = 0;
    for (int k = 0; k < NB; ++k) {
        int p = partials[m * NB + k];
        if (k < (int)blockIdx.x) prefix += p;
        total += p;
    }
    if (blockIdx.x == 0 && threadIdx.x == 0) off[n] = total;
    if (prefix != 0) {
        int tbase = blockIdx.x * SCAN_CHUNK + threadIdx.x * SCAN_EPT;
        #pragma unroll
        for (int k = 0; k < SCAN_EPT; ++k) {
            int i = tbase + k;
            if (i < n) off[i] += prefix;
        }
    }
}

// Atomic-free permuted fill: edges[off[r]+rank] = (col, val), theta folded into m2.
__global__ __launch_bounds__(256) void fill3_kernel(
    const int* __restrict__ r0, const int* __restrict__ col0, const float* __restrict__ v0,
    int n0, const int* __restrict__ off0, int2* __restrict__ e0,
    const int* __restrict__ r1, const int* __restrict__ col1, const float* __restrict__ v1,
    int n1, const int* __restrict__ off1, int2* __restrict__ e1,
    const int* __restrict__ r2, const int* __restrict__ col2, const float* __restrict__ v2,
    int n2, const int* __restrict__ off2, int2* __restrict__ e2,
    const unsigned short* __restrict__ rank,
    const float* __restrict__ theta)
{
    int g = blockIdx.x * blockDim.x + threadIdx.x;
    int i = g;
    if (i < n0) {
        int pos = off0[r0[i]] + (int)rank[g];
        e0[pos] = make_int2(col0[i], __float_as_int(v0[i]));
        return;
    }
    i -= n0;
    if (i < n1) {
        int pos = off1[r1[i]] + (int)rank[g];
        e1[pos] = make_int2(col1[i], __float_as_int(v1[i]));
        return;
    }
    i -= n1;
    if (i < n2) {
        int c = col2[i];
        int pos = off2[r2[i]] + (int)rank[g];
        e2[pos] = make_int2(c, __float_as_int(v2[i] * theta[c]));
    }
}

// ---------------- gather-side CSR SpMM ----------------
// One wave per row; lane = 2 features (float2). Edge stream read via scalar
// loads (wave-uniform readfirstlane offsets); unroll-4 keeps 4 row-gathers
// in flight. Single 512B row store, no atomics, no zero-init.
template<bool RELU>
__global__ __launch_bounds__(256) void spmm_csr_kernel(
    const int* __restrict__ off, const int2* __restrict__ edges,
    const float* __restrict__ dense, float* __restrict__ out, int nrows)
{
    int lane = threadIdx.x & 63;
    int r = blockIdx.x * 4 + (threadIdx.x >> 6);
    if (r >= nrows) return;
    int j   = __builtin_amdgcn_readfirstlane(off[r]);
    int end = __builtin_amdgcn_readfirstlane(off[r + 1]);
    const float2* __restrict__ d2 = (const float2*)dense;

    float2 a0 = make_float2(0.f, 0.f), a1 = make_float2(0.f, 0.f);
    for (; j + 4 <= end; j += 4) {
        int2 e0 = edges[j], e1 = edges[j + 1], e2 = edges[j + 2], e3 = edges[j + 3];
        float2 d0 = d2[(size_t)e0.x * HALF_CH + lane];
        float2 d1 = d2[(size_t)e1.x * HALF_CH + lane];
        float2 dd2 = d2[(size_t)e2.x * HALF_CH + lane];
        float2 d3 = d2[(size_t)e3.x * HALF_CH + lane];
        float v0 = __int_as_float(e0.y), v1 = __int_as_float(e1.y);
        float v2 = __int_as_float(e2.y), v3 = __int_as_float(e3.y);
        a0.x = fmaf(v0, d0.x, a0.x); a0.y = fmaf(v0, d0.y, a0.y);
        a1.x = fmaf(v1, d1.x, a1.x); a1.y = fmaf(v1, d1.y, a1.y);
        a0.x = fmaf(v2, dd2.x, a0.x); a0.y = fmaf(v2, dd2.y, a0.y);
        a1.x = fmaf(v3, d3.x, a1.x); a1.y = fmaf(v3, d3.y, a1.y);
    }
    for (; j < end; ++j) {
        int2 e0 = edges[j];
        float2 d0 = d2[(size_t)e0.x * HALF_CH + lane];
        float v0 = __int_as_float(e0.y);
        a0.x = fmaf(v0, d0.x, a0.x); a0.y = fmaf(v0, d0.y, a0.y);
    }
    float2 res = make_float2(a0.x + a1.x, a0.y + a1.y);
    if (RELU) { res.x = fmaxf(res.x, 0.f); res.y = fmaxf(res.y, 0.f); }
    ((float2*)out)[(size_t)r * HALF_CH + lane] = res;
}

// ---------------- fallback (round-0) atomic path ----------------

__global__ __launch_bounds__(256) void spmm_atomic_kernel(
    const int* __restrict__ rows, const int* __restrict__ cols,
    const float* __restrict__ vals, const float* __restrict__ theta,
    const float* __restrict__ dense, float* __restrict__ out, int nnz)
{
    int idx = blockIdx.x * blockDim.x + threadIdx.x;
    int e = idx >> 7;
    int f = idx & (OUT_CH - 1);
    if (e >= nnz) return;
    int r = rows[e];
    int c = cols[e];
    float v = vals[e];
    if (theta != nullptr) v *= theta[c];
    atomicAdd(&out[(size_t)r * OUT_CH + f], v * dense[(size_t)c * OUT_CH + f]);
}

__global__ __launch_bounds__(256) void relu_kernel(float* __restrict__ out, int n4)
{
    int i = blockIdx.x * blockDim.x + threadIdx.x;
    if (i >= n4) return;
    float4 v = ((float4*)out)[i];
    v.x = fmaxf(v.x, 0.f); v.y = fmaxf(v.y, 0.f);
    v.z = fmaxf(v.z, 0.f); v.w = fmaxf(v.w, 0.f);
    ((float4*)out)[i] = v;
}

// ---------------- launch ----------------

static inline size_t align16(size_t x) { return (x + 15) & ~(size_t)15; }

extern "C" void kernel_launch(void* const* d_in, const int* in_sizes, int n_in,
                              void* d_out, int out_size, void* d_ws, size_t ws_size,
                              hipStream_t stream)
{
    const int*   phi_idx   = (const int*)d_in[0];
    const float* phi_vals  = (const float*)d_in[1];
    const int*   phii_idx  = (const int*)d_in[2];
    const float* phii_vals = (const float*)d_in[3];
    const int*   feat_idx  = (const int*)d_in[4];
    const float* feat_vals = (const float*)d_in[5];
    const float* W         = (const float*)d_in[6];
    const float* theta     = (const float*)d_in[7];

    const int nnz_phi  = in_sizes[1];
    const int nnz_phii = in_sizes[3];
    const int nnz_feat = in_sizes[5];
    const int n_nodes  = in_sizes[7];
    const size_t dense_elems = (size_t)n_nodes * OUT_CH;
    const long long total_e = (long long)nnz_feat + nnz_phii + nnz_phi;

    const int NB = (n_nodes + SCAN_CHUNK - 1) / SCAN_CHUNK;

    // ---- workspace layout ----
    size_t p = 0;
    size_t filtered_off = p; p += align16(dense_elems * sizeof(float));
    size_t tmp_off      = p; p += align16(dense_elems * sizeof(float));  // rank[] overlaid here
    size_t offs_off     = p; p += align16((size_t)3 * (n_nodes + 1) * sizeof(int));
    size_t part_off     = p; p += align16((size_t)3 * (NB > 0 ? NB : 1) * sizeof(int));
    size_t ef_off       = p; p += align16((size_t)nnz_feat * sizeof(int2));
    size_t epi_off      = p; p += align16((size_t)nnz_phii * sizeof(int2));
    size_t ep_off       = p; p += align16((size_t)nnz_phi  * sizeof(int2));
    size_t need = p;
    // rank overlay needs total_e * 2 bytes inside tmp (dense_elems*4 bytes)
    bool rank_fits = (size_t)total_e * sizeof(unsigned short) <= dense_elems * sizeof(float);

    char* ws = (char*)d_ws;
    dim3 block(256);

    if (ws_size >= need && rank_fits && NB <= 4096) {
        float* filtered = (float*)(ws + filtered_off);
        float* tmp      = (float*)(ws + tmp_off);
        unsigned short* rank = (unsigned short*)(ws + tmp_off);  // dead until spmm2
        int* off_f  = (int*)(ws + offs_off);
        int* off_pi = off_f  + (n_nodes + 1);
        int* off_p  = off_pi + (n_nodes + 1);
        int* partials = (int*)(ws + part_off);
        int2* e_f  = (int2*)(ws + ef_off);
        int2* e_pi = (int2*)(ws + epi_off);
        int2* e_p  = (int2*)(ws + ep_off);

        hipMemsetAsync(off_f, 0, (size_t)3 * (n_nodes + 1) * sizeof(int), stream);

        dim3 grid_e((unsigned)((total_e + 255) / 256));

        hist3_rank_kernel<<<grid_e, block, 0, stream>>>(
            feat_idx, nnz_feat, off_f,
            phii_idx, nnz_phii, off_pi,
            phi_idx,  nnz_phi,  off_p, rank);

        dim3 grid_s(NB, 3);
        scan_local_kernel<<<grid_s, dim3(SCAN_TPB), 0, stream>>>(off_f, partials, n_nodes, NB);
        scan_fixup_kernel<<<grid_s, dim3(SCAN_TPB), 0, stream>>>(off_f, partials, n_nodes, NB);

        fill3_kernel<<<grid_e, block, 0, stream>>>(
            feat_idx, feat_idx + nnz_feat, feat_vals, nnz_feat, off_f,  e_f,
            phii_idx, phii_idx + nnz_phii, phii_vals, nnz_phii, off_pi, e_pi,
            phi_idx,  phi_idx  + nnz_phi,  phi_vals,  nnz_phi,  off_p,  e_p,
            rank, theta);

        dim3 grid_r((unsigned)((n_nodes + 3) / 4));
        spmm_csr_kernel<false><<<grid_r, block, 0, stream>>>(off_f,  e_f,  W,        filtered, n_nodes);
        spmm_csr_kernel<false><<<grid_r, block, 0, stream>>>(off_pi, e_pi, filtered, tmp,      n_nodes);
        spmm_csr_kernel<true ><<<grid_r, block, 0, stream>>>(off_p,  e_p,  tmp,      (float*)d_out, n_nodes);
    } else {
        // fallback: round-0 atomic path (needs only 2 dense buffers)
        float* filtered = (float*)ws;
        float* tmp      = filtered + dense_elems;
        hipMemsetAsync(filtered, 0, 2 * dense_elems * sizeof(float), stream);
        hipMemsetAsync(d_out, 0, (size_t)out_size * sizeof(float), stream);
        {
            long long t = (long long)nnz_feat * OUT_CH;
            spmm_atomic_kernel<<<dim3((unsigned)((t + 255) / 256)), block, 0, stream>>>(
                feat_idx, feat_idx + nnz_feat, feat_vals, nullptr, W, filtered, nnz_feat);
        }
        {
            long long t = (long long)nnz_phii * OUT_CH;
            spmm_atomic_kernel<<<dim3((unsigned)((t + 255) / 256)), block, 0, stream>>>(
                phii_idx, phii_idx + nnz_phii, phii_vals, nullptr, filtered, tmp, nnz_phii);
        }
        {
            long long t = (long long)nnz_phi * OUT_CH;
            spmm_atomic_kernel<<<dim3((unsigned)((t + 255) / 256)), block, 0, stream>>>(
                phi_idx, phi_idx + nnz_phi, phi_vals, theta, tmp, (float*)d_out, nnz_phi);
        }
        {
            int n4 = out_size / 4;
            relu_kernel<<<dim3((n4 + 255) / 256), block, 0, stream>>>((float*)d_out, n4);
        }
    }
}

// Round 4
// 328.862 us; speedup vs baseline: 3.4942x; 1.1707x over previous
//
#include <hip/hip_runtime.h>

// SparseGraphWaveletLayer: out = relu( (phi·diag(theta)) @ (phi_inv @ (F_sparse @ W)) )
// N=50000, IN_CH=256, OUT_CH=128, NNZ=800000 per sparse matrix.
//
// Round 3 -> 4: globally atomic-free CSR build via two-level bucketing.
// Round-3 evidence: 2.4M device atomics run at ~23/ns (fabric RMW ceiling),
// 103us for hist alone. New build: LDS histograms + dense per-block partials
// + two tiny scans give every block disjoint write ranges -> zero global
// atomics, ~100MB coalesced traffic total. Buckets of 64 rows; phase D bins
// each bucket to row order in LDS and emits off[] + row-sorted edges.

#define OUT_CH 128
#define HALF_CH 64
#define RPB 64            // rows per bucket
#define RPB_SHIFT 6
#define MAX_NB 800        // supports N <= 51200
#define EPB 8192          // edges per block in phases A/C (256 thr x 32)

// ---------------- Phase A: per-block bucket histograms (no global atomics) --

__global__ __launch_bounds__(256) void bucket_hist_kernel(
    const int* __restrict__ rows0, int n0,
    const int* __restrict__ rows1, int n1,
    const int* __restrict__ rows2, int n2,
    int* __restrict__ hist_part,        // [3][NBLK][NB]
    int NB, int NBLK)
{
    int m = blockIdx.y;
    const int* rows = (m == 0) ? rows0 : (m == 1) ? rows1 : rows2;
    int nnz         = (m == 0) ? n0    : (m == 1) ? n1    : n2;
    __shared__ int bins[MAX_NB];
    for (int b = threadIdx.x; b < NB; b += 256) bins[b] = 0;
    __syncthreads();
    int base = blockIdx.x * EPB;
    #pragma unroll 4
    for (int k = 0; k < EPB / 256; ++k) {
        int i = base + k * 256 + threadIdx.x;
        if (i < nnz) atomicAdd(&bins[rows[i] >> RPB_SHIFT], 1);
    }
    __syncthreads();
    int* out = hist_part + ((size_t)(m * NBLK + blockIdx.x)) * NB;
    for (int b = threadIdx.x; b < NB; b += 256) out[b] = bins[b];
}

// ---------------- Phase B1: exclusive scan over blocks per (m, bucket) ------

__global__ __launch_bounds__(256) void scan_blocks_kernel(
    int* __restrict__ hist_part, int* __restrict__ totals, int NB, int NBLK)
{
    int t = blockIdx.x * 256 + threadIdx.x;
    if (t >= 3 * NB) return;
    int m = t / NB, b = t - m * NB;
    int run = 0;
    for (int blk = 0; blk < NBLK; ++blk) {
        size_t idx = ((size_t)(m * NBLK + blk)) * NB + b;
        int x = hist_part[idx];
        hist_part[idx] = run;          // in-place exclusive
        run += x;
    }
    totals[t] = run;
}

// ---------------- Phase B2: exclusive scan over buckets per matrix ----------

__global__ __launch_bounds__(1024) void scan_buckets_kernel(
    const int* __restrict__ totals, int* __restrict__ bases, int NB)
{
    int m = blockIdx.x;
    int t = threadIdx.x;
    int x = (t < NB) ? totals[m * NB + t] : 0;
    int lane = t & 63, wid = t >> 6;
    int incl = x;
    #pragma unroll
    for (int s = 1; s < 64; s <<= 1) {
        int y = __shfl_up(incl, s);
        if (lane >= s) incl += y;
    }
    __shared__ int wtot[16];
    __shared__ int wbase[16];
    if (lane == 63) wtot[wid] = incl;
    __syncthreads();
    if (t == 0) {
        int run = 0;
        #pragma unroll
        for (int w = 0; w < 16; ++w) { int v = wtot[w]; wbase[w] = run; run += v; }
    }
    __syncthreads();
    if (t < NB) bases[m * NB + t] = wbase[wid] + incl - x;
}

// ---------------- Phase C: scatter edges into bucket-grouped array ----------
// Block write ranges precomputed (bases + in-place-scanned hist_part):
// only LDS cursor atomics. theta folded into matrix 2 here.

__global__ __launch_bounds__(256) void bucket_scatter_kernel(
    const int* __restrict__ rows0, const int* __restrict__ cols0, const float* __restrict__ vals0, int n0,
    const int* __restrict__ rows1, const int* __restrict__ cols1, const float* __restrict__ vals1, int n1,
    const int* __restrict__ rows2, const int* __restrict__ cols2, const float* __restrict__ vals2, int n2,
    const float* __restrict__ theta,
    const int* __restrict__ hist_part, const int* __restrict__ bases,
    int2* __restrict__ eb0, int2* __restrict__ eb1, int2* __restrict__ eb2,
    int NB, int NBLK)
{
    int m = blockIdx.y;
    const int* rows; const int* cols; const float* vals; int nnz; int2* eb;
    if (m == 0)      { rows = rows0; cols = cols0; vals = vals0; nnz = n0; eb = eb0; }
    else if (m == 1) { rows = rows1; cols = cols1; vals = vals1; nnz = n1; eb = eb1; }
    else             { rows = rows2; cols = cols2; vals = vals2; nnz = n2; eb = eb2; }

    __shared__ int cur[MAX_NB];
    const int* hp = hist_part + ((size_t)(m * NBLK + blockIdx.x)) * NB;
    const int* bs = bases + m * NB;
    for (int b = threadIdx.x; b < NB; b += 256) cur[b] = bs[b] + hp[b];
    __syncthreads();

    int base = blockIdx.x * EPB;
    bool fold = (m == 2);
    #pragma unroll 4
    for (int k = 0; k < EPB / 256; ++k) {
        int i = base + k * 256 + threadIdx.x;
        if (i < nnz) {
            int r = rows[i], c = cols[i];
            float v = vals[i];
            if (fold) v *= theta[c];
            int pos = atomicAdd(&cur[r >> RPB_SHIFT], 1);   // LDS atomic
            eb[pos] = make_int2(c | ((r & (RPB - 1)) << 16), __float_as_int(v));
        }
    }
}

// ---------------- Phase D: bin each bucket to row order, emit CSR + off -----

__global__ __launch_bounds__(256) void bucket_to_csr_kernel(
    const int2* __restrict__ eb0, const int2* __restrict__ eb1, const int2* __restrict__ eb2,
    int2* __restrict__ ec0, int2* __restrict__ ec1, int2* __restrict__ ec2,
    const int* __restrict__ bases,
    int* __restrict__ off,              // [3][n+1]
    int n0, int n1, int n2, int NB, int n)
{
    int m = blockIdx.y;
    int b = blockIdx.x;
    const int2* eb; int2* ec; int nnz;
    if (m == 0)      { eb = eb0; ec = ec0; nnz = n0; }
    else if (m == 1) { eb = eb1; ec = ec1; nnz = n1; }
    else             { eb = eb2; ec = ec2; nnz = n2; }
    int base = bases[m * NB + b];
    int end  = (b + 1 < NB) ? bases[m * NB + b + 1] : nnz;

    __shared__ int hist[RPB];
    __shared__ int cur[RPB];
    __shared__ int loc[RPB + 1];
    if (threadIdx.x < RPB) { hist[threadIdx.x] = 0; cur[threadIdx.x] = 0; }
    __syncthreads();
    for (int i = base + threadIdx.x; i < end; i += 256)
        atomicAdd(&hist[(eb[i].x >> 16) & (RPB - 1)], 1);
    __syncthreads();
    if (threadIdx.x < RPB) {               // wave 0: scan 64 counts
        int x = hist[threadIdx.x];
        int incl = x;
        #pragma unroll
        for (int s = 1; s < RPB; s <<= 1) {
            int y = __shfl_up(incl, s);
            if (threadIdx.x >= s) incl += y;
        }
        loc[threadIdx.x] = incl - x;
        if (threadIdx.x == RPB - 1) loc[RPB] = incl;
    }
    __syncthreads();
    if (threadIdx.x <= RPB) {
        int r = b * RPB + threadIdx.x;
        if (r <= n) off[(size_t)m * (n + 1) + r] = base + loc[threadIdx.x];
    }
    for (int i = base + threadIdx.x; i < end; i += 256) {
        int2 e = eb[i];
        int rl = (e.x >> 16) & (RPB - 1);
        int rk = atomicAdd(&cur[rl], 1);   // LDS atomic
        ec[base + loc[rl] + rk] = make_int2(e.x & 0xFFFF, e.y);
    }
}

// ---------------- gather-side CSR SpMM (unchanged from round 3) -------------

template<bool RELU>
__global__ __launch_bounds__(256) void spmm_csr_kernel(
    const int* __restrict__ off, const int2* __restrict__ edges,
    const float* __restrict__ dense, float* __restrict__ out, int nrows)
{
    int lane = threadIdx.x & 63;
    int r = blockIdx.x * 4 + (threadIdx.x >> 6);
    if (r >= nrows) return;
    int j   = __builtin_amdgcn_readfirstlane(off[r]);
    int end = __builtin_amdgcn_readfirstlane(off[r + 1]);
    const float2* __restrict__ d2 = (const float2*)dense;

    float2 a0 = make_float2(0.f, 0.f), a1 = make_float2(0.f, 0.f);
    for (; j + 4 <= end; j += 4) {
        int2 e0 = edges[j], e1 = edges[j + 1], e2 = edges[j + 2], e3 = edges[j + 3];
        float2 d0 = d2[(size_t)e0.x * HALF_CH + lane];
        float2 d1 = d2[(size_t)e1.x * HALF_CH + lane];
        float2 dd2 = d2[(size_t)e2.x * HALF_CH + lane];
        float2 d3 = d2[(size_t)e3.x * HALF_CH + lane];
        float v0 = __int_as_float(e0.y), v1 = __int_as_float(e1.y);
        float v2 = __int_as_float(e2.y), v3 = __int_as_float(e3.y);
        a0.x = fmaf(v0, d0.x, a0.x); a0.y = fmaf(v0, d0.y, a0.y);
        a1.x = fmaf(v1, d1.x, a1.x); a1.y = fmaf(v1, d1.y, a1.y);
        a0.x = fmaf(v2, dd2.x, a0.x); a0.y = fmaf(v2, dd2.y, a0.y);
        a1.x = fmaf(v3, d3.x, a1.x); a1.y = fmaf(v3, d3.y, a1.y);
    }
    for (; j < end; ++j) {
        int2 e0 = edges[j];
        float2 d0 = d2[(size_t)e0.x * HALF_CH + lane];
        float v0 = __int_as_float(e0.y);
        a0.x = fmaf(v0, d0.x, a0.x); a0.y = fmaf(v0, d0.y, a0.y);
    }
    float2 res = make_float2(a0.x + a1.x, a0.y + a1.y);
    if (RELU) { res.x = fmaxf(res.x, 0.f); res.y = fmaxf(res.y, 0.f); }
    ((float2*)out)[(size_t)r * HALF_CH + lane] = res;
}

// ---------------- fallback (round-0) atomic path ----------------

__global__ __launch_bounds__(256) void spmm_atomic_kernel(
    const int* __restrict__ rows, const int* __restrict__ cols,
    const float* __restrict__ vals, const float* __restrict__ theta,
    const float* __restrict__ dense, float* __restrict__ out, int nnz)
{
    int idx = blockIdx.x * blockDim.x + threadIdx.x;
    int e = idx >> 7;
    int f = idx & (OUT_CH - 1);
    if (e >= nnz) return;
    int r = rows[e];
    int c = cols[e];
    float v = vals[e];
    if (theta != nullptr) v *= theta[c];
    atomicAdd(&out[(size_t)r * OUT_CH + f], v * dense[(size_t)c * OUT_CH + f]);
}

__global__ __launch_bounds__(256) void relu_kernel(float* __restrict__ out, int n4)
{
    int i = blockIdx.x * blockDim.x + threadIdx.x;
    if (i >= n4) return;
    float4 v = ((float4*)out)[i];
    v.x = fmaxf(v.x, 0.f); v.y = fmaxf(v.y, 0.f);
    v.z = fmaxf(v.z, 0.f); v.w = fmaxf(v.w, 0.f);
    ((float4*)out)[i] = v;
}

// ---------------- launch ----------------

static inline size_t align16(size_t x) { return (x + 15) & ~(size_t)15; }

extern "C" void kernel_launch(void* const* d_in, const int* in_sizes, int n_in,
                              void* d_out, int out_size, void* d_ws, size_t ws_size,
                              hipStream_t stream)
{
    const int*   phi_idx   = (const int*)d_in[0];
    const float* phi_vals  = (const float*)d_in[1];
    const int*   phii_idx  = (const int*)d_in[2];
    const float* phii_vals = (const float*)d_in[3];
    const int*   feat_idx  = (const int*)d_in[4];
    const float* feat_vals = (const float*)d_in[5];
    const float* W         = (const float*)d_in[6];
    const float* theta     = (const float*)d_in[7];

    const int nnz_phi  = in_sizes[1];
    const int nnz_phii = in_sizes[3];
    const int nnz_feat = in_sizes[5];
    const int n_nodes  = in_sizes[7];
    const int in_ch    = in_sizes[6] / OUT_CH;
    const size_t dense_elems = (size_t)n_nodes * OUT_CH;
    const long long total_e = (long long)nnz_feat + nnz_phii + nnz_phi;

    const int NB = (n_nodes + RPB - 1) >> RPB_SHIFT;
    int max_nnz = nnz_feat > nnz_phii ? nnz_feat : nnz_phii;
    if (nnz_phi > max_nnz) max_nnz = nnz_phi;
    const int NBLK = (max_nnz + EPB - 1) / EPB;

    // ---- workspace layout ----
    size_t p = 0;
    size_t filtered_off = p; p += align16(dense_elems * sizeof(float));
    size_t tmp_off      = p; p += align16(dense_elems * sizeof(float));
    size_t off_off      = p; p += align16((size_t)3 * (n_nodes + 1) * sizeof(int));
    size_t hp_off       = p; p += align16((size_t)3 * NBLK * NB * sizeof(int));
    size_t tot_off      = p; p += align16((size_t)3 * NB * sizeof(int));
    size_t bas_off      = p; p += align16((size_t)3 * NB * sizeof(int));
    size_t eb_off       = p; p += align16((size_t)total_e * sizeof(int2));
    size_t ec_off       = p; p += align16((size_t)total_e * sizeof(int2));
    size_t need = p;

    char* ws = (char*)d_ws;
    dim3 block(256);

    bool fast_ok = (ws_size >= need) && (NB <= MAX_NB) && (n_nodes <= 51200) &&
                   (in_ch <= 65535);

    if (fast_ok) {
        float* filtered = (float*)(ws + filtered_off);
        float* tmp      = (float*)(ws + tmp_off);
        int* off_arr    = (int*)(ws + off_off);
        int* hist_part  = (int*)(ws + hp_off);
        int* totals     = (int*)(ws + tot_off);
        int* bases      = (int*)(ws + bas_off);
        int2* eb0 = (int2*)(ws + eb_off);
        int2* eb1 = eb0 + nnz_feat;
        int2* eb2 = eb1 + nnz_phii;
        int2* ec0 = (int2*)(ws + ec_off);
        int2* ec1 = ec0 + nnz_feat;
        int2* ec2 = ec1 + nnz_phii;

        const int* rows0 = feat_idx;  const int* cols0 = feat_idx + nnz_feat;
        const int* rows1 = phii_idx;  const int* cols1 = phii_idx + nnz_phii;
        const int* rows2 = phi_idx;   const int* cols2 = phi_idx  + nnz_phi;

        bucket_hist_kernel<<<dim3(NBLK, 3), block, 0, stream>>>(
            rows0, nnz_feat, rows1, nnz_phii, rows2, nnz_phi,
            hist_part, NB, NBLK);

        scan_blocks_kernel<<<dim3((3 * NB + 255) / 256), block, 0, stream>>>(
            hist_part, totals, NB, NBLK);

        scan_buckets_kernel<<<dim3(3), dim3(1024), 0, stream>>>(totals, bases, NB);

        bucket_scatter_kernel<<<dim3(NBLK, 3), block, 0, stream>>>(
            rows0, cols0, feat_vals, nnz_feat,
            rows1, cols1, phii_vals, nnz_phii,
            rows2, cols2, phi_vals,  nnz_phi,
            theta, hist_part, bases, eb0, eb1, eb2, NB, NBLK);

        bucket_to_csr_kernel<<<dim3(NB, 3), block, 0, stream>>>(
            eb0, eb1, eb2, ec0, ec1, ec2, bases, off_arr,
            nnz_feat, nnz_phii, nnz_phi, NB, n_nodes);

        int* off_f  = off_arr;
        int* off_pi = off_arr + (n_nodes + 1);
        int* off_p  = off_arr + 2 * (n_nodes + 1);

        dim3 grid_r((unsigned)((n_nodes + 3) / 4));
        spmm_csr_kernel<false><<<grid_r, block, 0, stream>>>(off_f,  ec0, W,        filtered, n_nodes);
        spmm_csr_kernel<false><<<grid_r, block, 0, stream>>>(off_pi, ec1, filtered, tmp,      n_nodes);
        spmm_csr_kernel<true ><<<grid_r, block, 0, stream>>>(off_p,  ec2, tmp,      (float*)d_out, n_nodes);
    } else {
        // fallback: round-0 atomic path (needs only 2 dense buffers)
        float* filtered = (float*)ws;
        float* tmp      = filtered + dense_elems;
        hipMemsetAsync(filtered, 0, 2 * dense_elems * sizeof(float), stream);
        hipMemsetAsync(d_out, 0, (size_t)out_size * sizeof(float), stream);
        {
            long long t = (long long)nnz_feat * OUT_CH;
            spmm_atomic_kernel<<<dim3((unsigned)((t + 255) / 256)), block, 0, stream>>>(
                feat_idx, feat_idx + nnz_feat, feat_vals, nullptr, W, filtered, nnz_feat);
        }
        {
            long long t = (long long)nnz_phii * OUT_CH;
            spmm_atomic_kernel<<<dim3((unsigned)((t + 255) / 256)), block, 0, stream>>>(
                phii_idx, phii_idx + nnz_phii, phii_vals, nullptr, filtered, tmp, nnz_phii);
        }
        {
            long long t = (long long)nnz_phi * OUT_CH;
            spmm_atomic_kernel<<<dim3((unsigned)((t + 255) / 256)), block, 0, stream>>>(
                phi_idx, phi_idx + nnz_phi, phi_vals, theta, tmp, (float*)d_out, nnz_phi);
        }
        {
            int n4 = out_size / 4;
            relu_kernel<<<dim3((n4 + 255) / 256), block, 0, stream>>>((float*)d_out, n4);
        }
    }
}